// Round 10
// baseline (780.870 us; speedup 1.0000x reference)
//
#include <hip/hip_runtime.h>
#include <hip/hip_bf16.h>
#include <stdint.h>

#define DIM 3072
#define SEQ 4096
#define NH 24
#define HD 128

typedef __hip_bfloat16 bf16;
typedef __bf16 bfv8 __attribute__((ext_vector_type(8)));
typedef float f32x4 __attribute__((ext_vector_type(4)));
typedef float f32x16 __attribute__((ext_vector_type(16)));
typedef unsigned short us4 __attribute__((ext_vector_type(4)));
typedef unsigned short us8 __attribute__((ext_vector_type(8)));

template <int N> struct ic { static constexpr int value = N; };

__device__ __forceinline__ void async16(void* lds, const void* g) {
  __builtin_amdgcn_global_load_lds((const __attribute__((address_space(1))) void*)g,
                                   (__attribute__((address_space(3))) void*)lds, 16, 0, 0);
}

__device__ __forceinline__ unsigned short f2bf(float f) {
  unsigned int u = __builtin_bit_cast(unsigned int, f);
  u += 0x7fffu + ((u >> 16) & 1u);
  return (unsigned short)(u >> 16);
}
__device__ __forceinline__ float bf2f(unsigned short b) {
  return __builtin_bit_cast(float, (unsigned int)b << 16);
}
__device__ __forceinline__ unsigned int cvtpk(float lo, float hi) {
  unsigned int r;
  asm("v_cvt_pk_bf16_f32 %0, %1, %2" : "=v"(r) : "v"(lo), "v"(hi));
  return r;
}
__device__ __forceinline__ void pl32swap(unsigned int& a, unsigned int& b) {
  asm volatile("v_permlane32_swap_b32 %0, %1" : "+v"(a), "+v"(b));
}
#if __has_builtin(__builtin_amdgcn_exp2f)
__device__ __forceinline__ float fexp2(float x) { return __builtin_amdgcn_exp2f(x); }
#else
__device__ __forceinline__ float fexp2(float x) { return exp2f(x); }
#endif

#define MFMA16(a, b, c) __builtin_amdgcn_mfma_f32_16x16x32_bf16((a), (b), (c), 0, 0, 0)
#define MFMA32(a, b, c) __builtin_amdgcn_mfma_f32_32x32x16_bf16((a), (b), (c), 0, 0, 0)

// ---------------- kernel 1: fp32 -> bf16 cast (hidden states) ----------------
__global__ __launch_bounds__(256) void k_cast(const float4* __restrict__ in,
                                              us4* __restrict__ o, int n4) {
  int i = blockIdx.x * 256 + threadIdx.x;
  if (i >= n4) return;
  float4 v = in[i];
  us4 r;
  r.x = f2bf(v.x); r.y = f2bf(v.y); r.z = f2bf(v.z); r.w = f2bf(v.w);
  o[i] = r;
}

// ------------- kernel 2: transpose-cast W (KxN fp32) -> WT (NxK bf16) -------------
__global__ __launch_bounds__(256) void k_transW(const float* __restrict__ W0,
    const float* __restrict__ W1, const float* __restrict__ W2,
    unsigned short* __restrict__ T0, unsigned short* __restrict__ T1,
    unsigned short* __restrict__ T2) {
  int z = blockIdx.z;
  const float* W = (z == 0) ? W0 : (z == 1) ? W1 : W2;
  unsigned short* T = (z == 0) ? T0 : (z == 1) ? T1 : T2;
  int kb = blockIdx.y * 64;
  int nb = blockIdx.x * 64;
  __shared__ float tile[64 * 64];
  int t = threadIdx.x;
#pragma unroll
  for (int p = 0; p < 4; ++p) {
    int cid = p * 256 + t;
    int row = cid >> 4, c4 = cid & 15;
    int slot = (c4 + (row >> 3)) & 15;
    float4 v = *(const float4*)&W[(size_t)(kb + row) * DIM + nb + c4 * 4];
    *(float4*)&tile[row * 64 + slot * 4] = v;
  }
  __syncthreads();
#pragma unroll
  for (int p = 0; p < 2; ++p) {
    int cid = p * 256 + t;
    int nl = cid >> 3, c8 = cid & 7;
    us8 o;
#pragma unroll
    for (int j = 0; j < 8; ++j) {
      int k = c8 * 8 + j;
      int slot = ((nl >> 2) + (k >> 3)) & 15;
      o[j] = f2bf(tile[k * 64 + slot * 4 + (nl & 3)]);
    }
    *(us8*)&T[(size_t)(nb + nl) * DIM + kb + c8 * 8] = o;
  }
}

// ------------- kernel 3: GEMM 256x256 tile, BK=32, 8 waves, 3-buf counted-vmcnt ----
// out[s][n] = hs[s][:] . WT[n][:] + bias[n]; output head-major bf16 out[h][s][d].
// Pipeline identical in shape to the R8 attn one (vmcnt(4), s_barrier, stage t+2).
// LDS swizzle: chunk c (16B) at row stored from global chunk c^((row>>1)&3) ->
// frag reads are 2-way-conflict (free). Wave-uniform gload_lds bases.
__global__ __launch_bounds__(512, 2) void k_gemm(const unsigned short* __restrict__ A,
    const unsigned short* __restrict__ B0, const unsigned short* __restrict__ B1,
    const unsigned short* __restrict__ B2, const float* __restrict__ c0,
    const float* __restrict__ c1, const float* __restrict__ c2,
    unsigned short* __restrict__ o0, unsigned short* __restrict__ o1,
    unsigned short* __restrict__ o2) {
  const int z = blockIdx.z;
  const unsigned short* Bt = (z == 0) ? B0 : (z == 1) ? B1 : B2;
  const float* bias = (z == 0) ? c0 : (z == 1) ? c1 : c2;
  unsigned short* outp = (z == 0) ? o0 : (z == 1) ? o1 : o2;
  const int nb = blockIdx.x * 256;
  const int mb = blockIdx.y * 256;
  const int tid = threadIdx.x;
  const int w = tid >> 6, l = tid & 63;
  const int wm = w >> 2, wn = w & 3;      // 2 x 4 wave grid; wave owns 128(M) x 64(N)
  const int lq = l & 15, lg = l >> 4;

  __shared__ unsigned short lA[3 * 8192];  // [3][256][32]
  __shared__ unsigned short lB[3 * 8192];

  // ---- staging pointers (per-lane global src, pre-swizzled; bumped 32/tile) ----
  const int srow0 = tid >> 2, srow1 = 128 + (tid >> 2);
  const int sc = tid & 3;
  const unsigned short* ap0 = A + (size_t)(mb + srow0) * DIM + ((sc ^ ((srow0 >> 1) & 3)) * 8);
  const unsigned short* ap1 = A + (size_t)(mb + srow1) * DIM + ((sc ^ ((srow1 >> 1) & 3)) * 8);
  const unsigned short* bp0 = Bt + (size_t)(nb + srow0) * DIM + ((sc ^ ((srow0 >> 1) & 3)) * 8);
  const unsigned short* bp1 = Bt + (size_t)(nb + srow1) * DIM + ((sc ^ ((srow1 >> 1) & 3)) * 8);
  const int dA0 = w * 512, dA1 = 4096 + w * 512;  // wave-uniform LDS dests (shorts)

#define GSTAGE(B)                                              \
  do {                                                         \
    async16(&lA[(B) * 8192 + dA0], ap0); ap0 += 32;            \
    async16(&lA[(B) * 8192 + dA1], ap1); ap1 += 32;            \
    async16(&lB[(B) * 8192 + dA0], bp0); bp0 += 32;            \
    async16(&lB[(B) * 8192 + dA1], bp1); bp1 += 32;            \
  } while (0)

  // ---- loop-invariant fragment read offsets ----
  int aOff[8], bOff[4];
#pragma unroll
  for (int mf = 0; mf < 8; ++mf) {
    int row = wm * 128 + mf * 16 + lq;
    aOff[mf] = row * 32 + ((lg ^ ((row >> 1) & 3)) * 8);
  }
#pragma unroll
  for (int nf = 0; nf < 4; ++nf) {
    int row = wn * 64 + nf * 16 + lq;
    bOff[nf] = row * 32 + ((lg ^ ((row >> 1) & 3)) * 8);
  }

  f32x4 acc[8][4];
#pragma unroll
  for (int i = 0; i < 8; ++i)
#pragma unroll
    for (int j = 0; j < 4; ++j) acc[i][j] = (f32x4){0.f, 0.f, 0.f, 0.f};

  GSTAGE(0);
  GSTAGE(1);

  auto tileG = [&](auto bufc, auto waitc, auto stagec) {
    constexpr int CUR = decltype(bufc)::value;
    constexpr int WAITN = decltype(waitc)::value;
    constexpr int DOSTAGE = decltype(stagec)::value;
    if constexpr (WAITN == 4)
      asm volatile("s_waitcnt vmcnt(4)" ::: "memory");
    else
      asm volatile("s_waitcnt vmcnt(0)" ::: "memory");
    __builtin_amdgcn_s_barrier();
    __builtin_amdgcn_sched_barrier(0);
    if constexpr (DOSTAGE) GSTAGE((CUR + 2) % 3);
    __builtin_amdgcn_sched_barrier(0);

    bfv8 bF[4];
#pragma unroll
    for (int nf = 0; nf < 4; ++nf) bF[nf] = *(const bfv8*)&lB[CUR * 8192 + bOff[nf]];
    __builtin_amdgcn_s_setprio(1);
#pragma unroll
    for (int mq = 0; mq < 4; ++mq) {
      bfv8 aF0 = *(const bfv8*)&lA[CUR * 8192 + aOff[2 * mq]];
      bfv8 aF1 = *(const bfv8*)&lA[CUR * 8192 + aOff[2 * mq + 1]];
#pragma unroll
      for (int nf = 0; nf < 4; ++nf) {
        acc[2 * mq][nf] = MFMA16(aF0, bF[nf], acc[2 * mq][nf]);
        acc[2 * mq + 1][nf] = MFMA16(aF1, bF[nf], acc[2 * mq + 1][nf]);
      }
    }
    __builtin_amdgcn_s_setprio(0);
  };

  // K = 3072 -> 96 K-tiles of 32. Tiles 0..92 via 31 iters, then 93,94,95.
  for (int it = 0; it < 31; ++it) {
    tileG(ic<0>{}, ic<4>{}, ic<1>{});
    tileG(ic<1>{}, ic<4>{}, ic<1>{});
    tileG(ic<2>{}, ic<4>{}, ic<1>{});
  }
  tileG(ic<0>{}, ic<4>{}, ic<1>{});  // t=93 stages t+2=95 -> buf 2
  tileG(ic<1>{}, ic<4>{}, ic<0>{});  // t=94
  tileG(ic<2>{}, ic<0>{}, ic<0>{});  // t=95

  // ---- epilogue: + bias, bf16 head-major ----
#pragma unroll
  for (int nf = 0; nf < 4; ++nf) {
    int n = nb + wn * 64 + nf * 16 + lq;
    float bv_ = bias[n];
    int hh = n >> 7, dd = n & 127;
    unsigned short* obase = outp + (size_t)hh * SEQ * HD + dd;
#pragma unroll
    for (int mf = 0; mf < 8; ++mf) {
      int srow = mb + wm * 128 + mf * 16 + lg * 4;
#pragma unroll
      for (int r = 0; r < 4; ++r)
        obase[(size_t)(srow + r) * HD] = f2bf(acc[mf][nf][r] + bv_);
    }
  }
#undef GSTAGE
}

// ------------- kernel 4: per-(h,s)-row RMSNorm + RoPE (in place, bf16) -------------
__global__ __launch_bounds__(256) void k_rmsrope(unsigned short* __restrict__ qb,
    unsigned short* __restrict__ kbuf, const float* __restrict__ cosT,
    const float* __restrict__ sinT, const float* __restrict__ gq,
    const float* __restrict__ gk) {
  int rowid = blockIdx.x * 4 + (threadIdx.x >> 6);
  int l = threadIdx.x & 63;
  int which = (rowid >= NH * SEQ) ? 1 : 0;
  int r2 = which ? rowid - NH * SEQ : rowid;
  int hh = r2 >> 12;
  int s = r2 & 4095;
  unsigned short* base = (which ? kbuf : qb) + ((size_t)hh * SEQ + s) * HD + 2 * l;
  const float* g = which ? gk : gq;
  unsigned int u = *(const unsigned int*)base;
  float x0 = bf2f((unsigned short)(u & 0xffffu));
  float x1 = bf2f((unsigned short)(u >> 16));
  float ss = x0 * x0 + x1 * x1;
#pragma unroll
  for (int o = 1; o < 64; o <<= 1) ss += __shfl_xor(ss, o);
  float rr = rsqrtf(ss * (1.0f / 128.0f) + 1e-6f);
  int d0 = 2 * l;
  float c0v = cosT[s * HD + d0], c1v = cosT[s * HD + d0 + 1];
  float s0v = sinT[s * HD + d0], s1v = sinT[s * HD + d0 + 1];
  float y0 = x0 * rr * g[d0];
  float y1 = x1 * rr * g[d0 + 1];
  float o0 = y0 * c0v - y1 * s0v;
  float o1 = y1 * c1v + y0 * s1v;
  if (!which) { o0 *= 0.1275174373f; o1 *= 0.1275174373f; } // log2(e)/sqrt(128)
  *(unsigned int*)base = (unsigned int)f2bf(o0) | ((unsigned int)f2bf(o1) << 16);
}

// ------------- kernel 5: V transpose  v[h][s][d] -> vt[h][d][s] -------------
__global__ __launch_bounds__(256) void k_transV(const unsigned short* __restrict__ vb,
                                                unsigned short* __restrict__ vt) {
  int hh = blockIdx.y;
  int sb = blockIdx.x * 64;
  __shared__ unsigned short tile[64 * 128];
  int t = threadIdx.x;
#pragma unroll
  for (int p = 0; p < 4; ++p) {
    int cid = p * 256 + t;
    int row = cid >> 4, c = cid & 15;
    int slot = (c + (row >> 3)) & 15;
    us8 v = *(const us8*)&vb[((size_t)hh * SEQ + sb + row) * HD + c * 8];
    *(us8*)&tile[row * 128 + slot * 8] = v;
  }
  __syncthreads();
#pragma unroll
  for (int p = 0; p < 4; ++p) {
    int cid = p * 256 + t;
    int d = cid >> 3, c8 = cid & 7;
    us8 o;
#pragma unroll
    for (int j = 0; j < 8; ++j) {
      int s = c8 * 8 + j;
      int slot = ((d >> 3) + (s >> 3)) & 15;
      o[j] = tile[s * 128 + slot * 8 + (d & 7)];
    }
    *(us8*)&vt[((size_t)hh * HD + d) * SEQ + sb + c8 * 8] = o;
  }
}

// ------------- kernel 6: flash attention, 32x32 MFMA, max-free softmax -------------
// R10: QK accumulator split into two chains (halved MFMA dep chain).
__global__ __launch_bounds__(256, 3) void k_attn(const unsigned short* __restrict__ qg,
    const unsigned short* __restrict__ kg, const unsigned short* __restrict__ vtg,
    float* __restrict__ outp) {
  const int h = blockIdx.y;
  const int qb0 = blockIdx.x * 128;
  const int t = threadIdx.x;
  const int w = t >> 6, l = t & 63;
  const int l31 = l & 31, hi = l >> 5;

  __shared__ unsigned short lKf[3 * 4096];  // [3][32][128]
  __shared__ unsigned short lVf[3 * 4096];  // [3][128][32]

  bfv8 qf[8];
  {
    const unsigned short* qrow = qg + ((size_t)h * SEQ + qb0 + w * 32 + l31) * HD + hi * 8;
#pragma unroll
    for (int ks = 0; ks < 8; ++ks) qf[ks] = *(const bfv8*)(qrow + ks * 16);
  }

  int kidx[8], vidx[4][2];
#pragma unroll
  for (int ks = 0; ks < 8; ++ks)
    kidx[ks] = l31 * 128 + (((ks * 2 + hi) ^ (l31 & 7) ^ ((l31 >> 3) & 1)) * 8);
#pragma unroll
  for (int dt = 0; dt < 4; ++dt)
#pragma unroll
    for (int ksub = 0; ksub < 2; ++ksub)
      vidx[dt][ksub] =
          (dt * 32 + l31) * 32 + (((ksub * 2 + hi) ^ (l31 & 3) ^ ((l31 >> 2) & 3)) * 8);

  const unsigned short *kp0, *kp1, *vp0, *vp1;
  {
    int kr0 = w * 4 + (l >> 4), kr1 = 16 + kr0;
    kp0 = kg + ((size_t)h * SEQ + kr0) * HD + (((l & 15) ^ (kr0 & 7) ^ ((kr0 >> 3) & 1)) * 8);
    kp1 = kg + ((size_t)h * SEQ + kr1) * HD + (((l & 15) ^ (kr1 & 7) ^ ((kr1 >> 3) & 1)) * 8);
    int vr0 = w * 16 + (l >> 2), vr1 = 64 + vr0;
    vp0 = vtg + ((size_t)h * HD + vr0) * SEQ + (((l & 3) ^ (vr0 & 3) ^ ((vr0 >> 2) & 3)) * 8);
    vp1 = vtg + ((size_t)h * HD + vr1) * SEQ + (((l & 3) ^ (vr1 & 3) ^ ((vr1 >> 2) & 3)) * 8);
  }

#define STAGE(B)                                                        \
  do {                                                                  \
    async16(&lKf[(B) * 4096 + w * 512], kp0);        kp0 += 32 * HD;    \
    async16(&lKf[(B) * 4096 + 2048 + w * 512], kp1); kp1 += 32 * HD;    \
    async16(&lVf[(B) * 4096 + w * 512], vp0);        vp0 += 32;         \
    async16(&lVf[(B) * 4096 + 2048 + w * 512], vp1); vp1 += 32;         \
  } while (0)

  f32x16 oacc[4];
#pragma unroll
  for (int dt = 0; dt < 4; ++dt)
#pragma unroll
    for (int r = 0; r < 16; ++r) oacc[dt][r] = 0.f;
  float l_run = 0.f;

  STAGE(0);
  STAGE(1);

  auto tile = [&](auto bufc, auto waitc, auto stagec) {
    constexpr int CUR = decltype(bufc)::value;
    constexpr int WAITN = decltype(waitc)::value;
    constexpr int DOSTAGE = decltype(stagec)::value;
    if constexpr (WAITN == 4)
      asm volatile("s_waitcnt vmcnt(4)" ::: "memory");
    else
      asm volatile("s_waitcnt vmcnt(0)" ::: "memory");
    __builtin_amdgcn_s_barrier();
    __builtin_amdgcn_sched_barrier(0);
    if constexpr (DOSTAGE) STAGE((CUR + 2) % 3);
    __builtin_amdgcn_sched_barrier(0);

    // ---- S^T = K . Q^T : two independent 4-chains, then combine ----
    f32x16 sa, sb;
#pragma unroll
    for (int r = 0; r < 16; ++r) { sa[r] = 0.f; sb[r] = 0.f; }
    __builtin_amdgcn_s_setprio(1);
#pragma unroll
    for (int ks = 0; ks < 4; ++ks) {
      bfv8 kfa = *(const bfv8*)&lKf[CUR * 4096 + kidx[ks]];
      bfv8 kfb = *(const bfv8*)&lKf[CUR * 4096 + kidx[ks + 4]];
      sa = MFMA32(kfa, qf[ks], sa);
      sb = MFMA32(kfb, qf[ks + 4], sb);
    }
    __builtin_amdgcn_s_setprio(0);
    f32x16 st = sa + sb;

    // ---- max-free softmax: P = exp2(S), l += sum ----
#pragma unroll
    for (int r = 0; r < 16; ++r) st[r] = fexp2(st[r]);
    float s01 = st[0] + st[1], s23 = st[2] + st[3];
    float s45 = st[4] + st[5], s67 = st[6] + st[7];
    float s89 = st[8] + st[9], sab = st[10] + st[11];
    float scd = st[12] + st[13], sef = st[14] + st[15];
    float lsum = ((s01 + s23) + (s45 + s67)) + ((s89 + sab) + (scd + sef));
    lsum += __shfl_xor(lsum, 32);
    l_run += lsum;

    // ---- pack P into PV A-frags ----
    bfv8 pa[2];
    {
      unsigned int a0 = cvtpk(st[0], st[1]), a1 = cvtpk(st[2], st[3]);
      unsigned int b0 = cvtpk(st[4], st[5]), b1 = cvtpk(st[6], st[7]);
      unsigned int c0 = cvtpk(st[8], st[9]), c1 = cvtpk(st[10], st[11]);
      unsigned int d0 = cvtpk(st[12], st[13]), d1 = cvtpk(st[14], st[15]);
      pl32swap(a0, b0); pl32swap(a1, b1); pl32swap(c0, d0); pl32swap(c1, d1);
      pa[0] = __builtin_bit_cast(bfv8, make_uint4(a0, a1, b0, b1));
      pa[1] = __builtin_bit_cast(bfv8, make_uint4(c0, c1, d0, d1));
    }

    // ---- O += P . V ----
    __builtin_amdgcn_s_setprio(1);
#pragma unroll
    for (int dt = 0; dt < 4; ++dt)
#pragma unroll
      for (int ksub = 0; ksub < 2; ++ksub) {
        bfv8 vf = *(const bfv8*)&lVf[CUR * 4096 + vidx[dt][ksub]];
        oacc[dt] = MFMA32(pa[ksub], vf, oacc[dt]);
      }
    __builtin_amdgcn_s_setprio(0);
  };

  for (int it = 0; it < 42; ++it) {
    tile(ic<0>{}, ic<4>{}, ic<1>{});
    tile(ic<1>{}, ic<4>{}, ic<1>{});
    tile(ic<2>{}, ic<4>{}, ic<1>{});
  }
  tile(ic<0>{}, ic<4>{}, ic<0>{});
  tile(ic<1>{}, ic<0>{}, ic<0>{});

  float linv = 1.0f / l_run;
#pragma unroll
  for (int r = 0; r < 16; ++r) {
    int qr = (r & 3) + 8 * (r >> 2) + 4 * hi;
    float lr = __shfl(linv, qr);
    float* orow = outp + (size_t)(qb0 + w * 32 + qr) * DIM + h * HD;
#pragma unroll
    for (int dt = 0; dt < 4; ++dt) orow[dt * 32 + l31] = oacc[dt][r] * lr;
  }
#undef STAGE
}

extern "C" void kernel_launch(void* const* d_in, const int* in_sizes, int n_in,
                              void* d_out, int out_size, void* d_ws, size_t ws_size,
                              hipStream_t stream) {
  const float* hs = (const float*)d_in[0];
  const float* cosT = (const float*)d_in[1];
  const float* sinT = (const float*)d_in[2];
  const float* Wq = (const float*)d_in[3];
  const float* bq = (const float*)d_in[4];
  const float* Wk = (const float*)d_in[5];
  const float* bk = (const float*)d_in[6];
  const float* Wv = (const float*)d_in[7];
  const float* bv = (const float*)d_in[8];
  const float* gq = (const float*)d_in[9];
  const float* gk = (const float*)d_in[10];
  float* out = (float*)d_out;

  char* ws = (char*)d_ws;
  const size_t SZ_HS = (size_t)SEQ * DIM * 2;
  const size_t SZ_W = (size_t)DIM * DIM * 2;
  const size_t SZ_HEAD = (size_t)NH * SEQ * HD * 2;
  unsigned short* hsb = (unsigned short*)ws;               ws += SZ_HS;
  unsigned short* WqT = (unsigned short*)ws;               ws += SZ_W;
  unsigned short* WkT = (unsigned short*)ws;               ws += SZ_W;
  unsigned short* WvT = (unsigned short*)ws;               ws += SZ_W;
  unsigned short* q_b = (unsigned short*)ws;               ws += SZ_HEAD;
  unsigned short* k_b = (unsigned short*)ws;               ws += SZ_HEAD;
  unsigned short* v_b = (unsigned short*)ws;               ws += SZ_HEAD;
  unsigned short* vtr = (unsigned short*)ws;               ws += SZ_HEAD;

  int n4 = SEQ * DIM / 4;
  k_cast<<<dim3(n4 / 256), dim3(256), 0, stream>>>((const float4*)hs, (us4*)hsb, n4);
  k_transW<<<dim3(48, 48, 3), dim3(256), 0, stream>>>(Wq, Wk, Wv, WqT, WkT, WvT);
  k_gemm<<<dim3(12, 16, 3), dim3(512), 0, stream>>>(hsb, WqT, WkT, WvT, bq, bk, bv,
                                                    q_b, k_b, v_b);
  k_rmsrope<<<dim3(2 * NH * SEQ / 4), dim3(256), 0, stream>>>(q_b, k_b, cosT, sinT, gq, gk);
  k_transV<<<dim3(64, 24), dim3(256), 0, stream>>>(v_b, vtr);
  k_attn<<<dim3(32, 24), dim3(256), 0, stream>>>(q_b, k_b, vtr, out);
}

// Round 11
// 570.712 us; speedup vs baseline: 1.3682x; 1.3682x over previous
//
#include <hip/hip_runtime.h>
#include <hip/hip_bf16.h>
#include <stdint.h>

#define DIM 3072
#define SEQ 4096
#define NH 24
#define HD 128

typedef __hip_bfloat16 bf16;
typedef __bf16 bfv8 __attribute__((ext_vector_type(8)));
typedef float f32x4 __attribute__((ext_vector_type(4)));
typedef float f32x16 __attribute__((ext_vector_type(16)));
typedef unsigned short us4 __attribute__((ext_vector_type(4)));
typedef unsigned short us8 __attribute__((ext_vector_type(8)));

template <int N> struct ic { static constexpr int value = N; };

__device__ __forceinline__ void async16(void* lds, const void* g) {
  __builtin_amdgcn_global_load_lds((const __attribute__((address_space(1))) void*)g,
                                   (__attribute__((address_space(3))) void*)lds, 16, 0, 0);
}

__device__ __forceinline__ unsigned short f2bf(float f) {
  unsigned int u = __builtin_bit_cast(unsigned int, f);
  u += 0x7fffu + ((u >> 16) & 1u);
  return (unsigned short)(u >> 16);
}
__device__ __forceinline__ float bf2f(unsigned short b) {
  return __builtin_bit_cast(float, (unsigned int)b << 16);
}
__device__ __forceinline__ unsigned int cvtpk(float lo, float hi) {
  unsigned int r;
  asm("v_cvt_pk_bf16_f32 %0, %1, %2" : "=v"(r) : "v"(lo), "v"(hi));
  return r;
}
__device__ __forceinline__ void pl32swap(unsigned int& a, unsigned int& b) {
  asm volatile("v_permlane32_swap_b32 %0, %1" : "+v"(a), "+v"(b));
}
#if __has_builtin(__builtin_amdgcn_exp2f)
__device__ __forceinline__ float fexp2(float x) { return __builtin_amdgcn_exp2f(x); }
#else
__device__ __forceinline__ float fexp2(float x) { return exp2f(x); }
#endif

#define MFMA16(a, b, c) __builtin_amdgcn_mfma_f32_16x16x32_bf16((a), (b), (c), 0, 0, 0)
#define MFMA32(a, b, c) __builtin_amdgcn_mfma_f32_32x32x16_bf16((a), (b), (c), 0, 0, 0)

// ---------------- kernel 1: fp32 -> bf16 cast (hidden states) ----------------
__global__ __launch_bounds__(256) void k_cast(const float4* __restrict__ in,
                                              us4* __restrict__ o, int n4) {
  int i = blockIdx.x * 256 + threadIdx.x;
  if (i >= n4) return;
  float4 v = in[i];
  us4 r;
  r.x = f2bf(v.x); r.y = f2bf(v.y); r.z = f2bf(v.z); r.w = f2bf(v.w);
  o[i] = r;
}

// ------------- kernel 2: transpose-cast W (KxN fp32) -> WT (NxK bf16) -------------
__global__ __launch_bounds__(256) void k_transW(const float* __restrict__ W0,
    const float* __restrict__ W1, const float* __restrict__ W2,
    unsigned short* __restrict__ T0, unsigned short* __restrict__ T1,
    unsigned short* __restrict__ T2) {
  int z = blockIdx.z;
  const float* W = (z == 0) ? W0 : (z == 1) ? W1 : W2;
  unsigned short* T = (z == 0) ? T0 : (z == 1) ? T1 : T2;
  int kb = blockIdx.y * 64;
  int nb = blockIdx.x * 64;
  __shared__ float tile[64 * 64];
  int t = threadIdx.x;
#pragma unroll
  for (int p = 0; p < 4; ++p) {
    int cid = p * 256 + t;
    int row = cid >> 4, c4 = cid & 15;
    int slot = (c4 + (row >> 3)) & 15;
    float4 v = *(const float4*)&W[(size_t)(kb + row) * DIM + nb + c4 * 4];
    *(float4*)&tile[row * 64 + slot * 4] = v;
  }
  __syncthreads();
#pragma unroll
  for (int p = 0; p < 2; ++p) {
    int cid = p * 256 + t;
    int nl = cid >> 3, c8 = cid & 7;
    us8 o;
#pragma unroll
    for (int j = 0; j < 8; ++j) {
      int k = c8 * 8 + j;
      int slot = ((nl >> 2) + (k >> 3)) & 15;
      o[j] = f2bf(tile[k * 64 + slot * 4 + (nl & 3)]);
    }
    *(us8*)&T[(size_t)(nb + nl) * DIM + kb + c8 * 8] = o;
  }
}

// ------------- kernel 3: GEMM  out[s][n] = hs[s][:] . WT[n][:] + bias[n] -------------
// 128x128 tile, BK=64, 4 waves. R11: launch_bounds (256,3) -> 3 blocks/CU
// (was (256,2); reg usage ~64 AGPR + ~85 VGPR fits the 3-wave/EU cap).
__global__ __launch_bounds__(256, 3) void k_gemm(const unsigned short* __restrict__ A,
    const unsigned short* __restrict__ B0, const unsigned short* __restrict__ B1,
    const unsigned short* __restrict__ B2, const float* __restrict__ c0,
    const float* __restrict__ c1, const float* __restrict__ c2,
    unsigned short* __restrict__ o0, unsigned short* __restrict__ o1,
    unsigned short* __restrict__ o2) {
  const int z = blockIdx.z;
  const unsigned short* Bt = (z == 0) ? B0 : (z == 1) ? B1 : B2;
  const float* bias = (z == 0) ? c0 : (z == 1) ? c1 : c2;
  unsigned short* outp = (z == 0) ? o0 : (z == 1) ? o1 : o2;
  const int nb = blockIdx.x * 128;
  const int mb = blockIdx.y * 128;
  const int t = threadIdx.x;
  const int w = t >> 6, l = t & 63;
  const int wr = w >> 1, wc = w & 1;
  const int lq = l & 15, lg = l >> 4;
  __shared__ unsigned short lA[128 * 64];
  __shared__ unsigned short lB[128 * 64];
  f32x4 acc[4][4];
#pragma unroll
  for (int i = 0; i < 4; ++i)
#pragma unroll
    for (int j = 0; j < 4; ++j) acc[i][j] = (f32x4){0.f, 0.f, 0.f, 0.f};

  for (int kb = 0; kb < DIM; kb += 64) {
    __syncthreads();
#pragma unroll
    for (int r = 0; r < 4; ++r) {
      int row = (w * 4 + r) * 8 + (l >> 3);
      int sl = (l & 7) ^ (row & 7);
      async16(&lA[(w * 4 + r) * 512], A + (size_t)(mb + row) * DIM + kb + sl * 8);
      async16(&lB[(w * 4 + r) * 512], Bt + (size_t)(nb + row) * DIM + kb + sl * 8);
    }
    __syncthreads();
#pragma unroll
    for (int kc = 0; kc < 2; ++kc) {
      bfv8 af[4], bfv[4];
#pragma unroll
      for (int mf = 0; mf < 4; ++mf) {
        int row = wr * 64 + mf * 16 + lq;
        af[mf] = *(const bfv8*)&lA[row * 64 + (((kc * 4 + lg) ^ (row & 7)) * 8)];
      }
#pragma unroll
      for (int nf = 0; nf < 4; ++nf) {
        int row = wc * 64 + nf * 16 + lq;
        bfv[nf] = *(const bfv8*)&lB[row * 64 + (((kc * 4 + lg) ^ (row & 7)) * 8)];
      }
#pragma unroll
      for (int mf = 0; mf < 4; ++mf)
#pragma unroll
        for (int nf = 0; nf < 4; ++nf)
          acc[mf][nf] = MFMA16(af[mf], bfv[nf], acc[mf][nf]);
    }
  }
#pragma unroll
  for (int nf = 0; nf < 4; ++nf) {
    int n = nb + wc * 64 + nf * 16 + lq;
    float bv_ = bias[n];
    int hh = n >> 7, dd = n & 127;
    unsigned short* obase = outp + (size_t)hh * SEQ * HD + dd;
#pragma unroll
    for (int mf = 0; mf < 4; ++mf) {
      int srow = mb + wr * 64 + mf * 16 + lg * 4;
#pragma unroll
      for (int r = 0; r < 4; ++r)
        obase[(size_t)(srow + r) * HD] = f2bf(acc[mf][nf][r] + bv_);
    }
  }
}

// ------------- kernel 4: per-(h,s)-row RMSNorm + RoPE (in place, bf16) -------------
__global__ __launch_bounds__(256) void k_rmsrope(unsigned short* __restrict__ qb,
    unsigned short* __restrict__ kbuf, const float* __restrict__ cosT,
    const float* __restrict__ sinT, const float* __restrict__ gq,
    const float* __restrict__ gk) {
  int rowid = blockIdx.x * 4 + (threadIdx.x >> 6);
  int l = threadIdx.x & 63;
  int which = (rowid >= NH * SEQ) ? 1 : 0;
  int r2 = which ? rowid - NH * SEQ : rowid;
  int hh = r2 >> 12;
  int s = r2 & 4095;
  unsigned short* base = (which ? kbuf : qb) + ((size_t)hh * SEQ + s) * HD + 2 * l;
  const float* g = which ? gk : gq;
  unsigned int u = *(const unsigned int*)base;
  float x0 = bf2f((unsigned short)(u & 0xffffu));
  float x1 = bf2f((unsigned short)(u >> 16));
  float ss = x0 * x0 + x1 * x1;
#pragma unroll
  for (int o = 1; o < 64; o <<= 1) ss += __shfl_xor(ss, o);
  float rr = rsqrtf(ss * (1.0f / 128.0f) + 1e-6f);
  int d0 = 2 * l;
  float c0v = cosT[s * HD + d0], c1v = cosT[s * HD + d0 + 1];
  float s0v = sinT[s * HD + d0], s1v = sinT[s * HD + d0 + 1];
  float y0 = x0 * rr * g[d0];
  float y1 = x1 * rr * g[d0 + 1];
  float o0 = y0 * c0v - y1 * s0v;
  float o1 = y1 * c1v + y0 * s1v;
  if (!which) { o0 *= 0.1275174373f; o1 *= 0.1275174373f; } // log2(e)/sqrt(128)
  *(unsigned int*)base = (unsigned int)f2bf(o0) | ((unsigned int)f2bf(o1) << 16);
}

// ------------- kernel 5: V transpose  v[h][s][d] -> vt[h][d][s] -------------
__global__ __launch_bounds__(256) void k_transV(const unsigned short* __restrict__ vb,
                                                unsigned short* __restrict__ vt) {
  int hh = blockIdx.y;
  int sb = blockIdx.x * 64;
  __shared__ unsigned short tile[64 * 128];
  int t = threadIdx.x;
#pragma unroll
  for (int p = 0; p < 4; ++p) {
    int cid = p * 256 + t;
    int row = cid >> 4, c = cid & 15;
    int slot = (c + (row >> 3)) & 15;
    us8 v = *(const us8*)&vb[((size_t)hh * SEQ + sb + row) * HD + c * 8];
    *(us8*)&tile[row * 128 + slot * 8] = v;
  }
  __syncthreads();
#pragma unroll
  for (int p = 0; p < 4; ++p) {
    int cid = p * 256 + t;
    int d = cid >> 3, c8 = cid & 7;
    us8 o;
#pragma unroll
    for (int j = 0; j < 8; ++j) {
      int s = c8 * 8 + j;
      int slot = ((d >> 3) + (s >> 3)) & 15;
      o[j] = tile[s * 128 + slot * 8 + (d & 7)];
    }
    *(us8*)&vt[((size_t)hh * HD + d) * SEQ + sb + c8 * 8] = o;
  }
}

// ------------- kernel 6: flash attention (R9-exact: single QK chain) -------------
__global__ __launch_bounds__(256, 3) void k_attn(const unsigned short* __restrict__ qg,
    const unsigned short* __restrict__ kg, const unsigned short* __restrict__ vtg,
    float* __restrict__ outp) {
  const int h = blockIdx.y;
  const int qb0 = blockIdx.x * 128;
  const int t = threadIdx.x;
  const int w = t >> 6, l = t & 63;
  const int l31 = l & 31, hi = l >> 5;

  __shared__ unsigned short lKf[3 * 4096];  // [3][32][128]
  __shared__ unsigned short lVf[3 * 4096];  // [3][128][32]

  bfv8 qf[8];
  {
    const unsigned short* qrow = qg + ((size_t)h * SEQ + qb0 + w * 32 + l31) * HD + hi * 8;
#pragma unroll
    for (int ks = 0; ks < 8; ++ks) qf[ks] = *(const bfv8*)(qrow + ks * 16);
  }

  int kidx[8], vidx[4][2];
#pragma unroll
  for (int ks = 0; ks < 8; ++ks)
    kidx[ks] = l31 * 128 + (((ks * 2 + hi) ^ (l31 & 7) ^ ((l31 >> 3) & 1)) * 8);
#pragma unroll
  for (int dt = 0; dt < 4; ++dt)
#pragma unroll
    for (int ksub = 0; ksub < 2; ++ksub)
      vidx[dt][ksub] =
          (dt * 32 + l31) * 32 + (((ksub * 2 + hi) ^ (l31 & 3) ^ ((l31 >> 2) & 3)) * 8);

  const unsigned short *kp0, *kp1, *vp0, *vp1;
  {
    int kr0 = w * 4 + (l >> 4), kr1 = 16 + kr0;
    kp0 = kg + ((size_t)h * SEQ + kr0) * HD + (((l & 15) ^ (kr0 & 7) ^ ((kr0 >> 3) & 1)) * 8);
    kp1 = kg + ((size_t)h * SEQ + kr1) * HD + (((l & 15) ^ (kr1 & 7) ^ ((kr1 >> 3) & 1)) * 8);
    int vr0 = w * 16 + (l >> 2), vr1 = 64 + vr0;
    vp0 = vtg + ((size_t)h * HD + vr0) * SEQ + (((l & 3) ^ (vr0 & 3) ^ ((vr0 >> 2) & 3)) * 8);
    vp1 = vtg + ((size_t)h * HD + vr1) * SEQ + (((l & 3) ^ (vr1 & 3) ^ ((vr1 >> 2) & 3)) * 8);
  }

#define STAGE(B)                                                        \
  do {                                                                  \
    async16(&lKf[(B) * 4096 + w * 512], kp0);        kp0 += 32 * HD;    \
    async16(&lKf[(B) * 4096 + 2048 + w * 512], kp1); kp1 += 32 * HD;    \
    async16(&lVf[(B) * 4096 + w * 512], vp0);        vp0 += 32;         \
    async16(&lVf[(B) * 4096 + 2048 + w * 512], vp1); vp1 += 32;         \
  } while (0)

  f32x16 oacc[4];
#pragma unroll
  for (int dt = 0; dt < 4; ++dt)
#pragma unroll
    for (int r = 0; r < 16; ++r) oacc[dt][r] = 0.f;
  float l_run = 0.f;

  STAGE(0);
  STAGE(1);

  auto tile = [&](auto bufc, auto waitc, auto stagec) {
    constexpr int CUR = decltype(bufc)::value;
    constexpr int WAITN = decltype(waitc)::value;
    constexpr int DOSTAGE = decltype(stagec)::value;
    if constexpr (WAITN == 4)
      asm volatile("s_waitcnt vmcnt(4)" ::: "memory");
    else
      asm volatile("s_waitcnt vmcnt(0)" ::: "memory");
    __builtin_amdgcn_s_barrier();
    __builtin_amdgcn_sched_barrier(0);
    if constexpr (DOSTAGE) STAGE((CUR + 2) % 3);
    __builtin_amdgcn_sched_barrier(0);

    // ---- S^T = K . Q^T (one 32x32 tile) ----
    f32x16 st;
#pragma unroll
    for (int r = 0; r < 16; ++r) st[r] = 0.f;
    __builtin_amdgcn_s_setprio(1);
#pragma unroll
    for (int ks = 0; ks < 8; ++ks) {
      bfv8 kf = *(const bfv8*)&lKf[CUR * 4096 + kidx[ks]];
      st = MFMA32(kf, qf[ks], st);
    }
    __builtin_amdgcn_s_setprio(0);

    // ---- max-free softmax: P = exp2(S), l += sum ----
#pragma unroll
    for (int r = 0; r < 16; ++r) st[r] = fexp2(st[r]);
    float s01 = st[0] + st[1], s23 = st[2] + st[3];
    float s45 = st[4] + st[5], s67 = st[6] + st[7];
    float s89 = st[8] + st[9], sab = st[10] + st[11];
    float scd = st[12] + st[13], sef = st[14] + st[15];
    float lsum = ((s01 + s23) + (s45 + s67)) + ((s89 + sab) + (scd + sef));
    lsum += __shfl_xor(lsum, 32);
    l_run += lsum;

    // ---- pack P into PV A-frags ----
    bfv8 pa[2];
    {
      unsigned int a0 = cvtpk(st[0], st[1]), a1 = cvtpk(st[2], st[3]);
      unsigned int b0 = cvtpk(st[4], st[5]), b1 = cvtpk(st[6], st[7]);
      unsigned int c0 = cvtpk(st[8], st[9]), c1 = cvtpk(st[10], st[11]);
      unsigned int d0 = cvtpk(st[12], st[13]), d1 = cvtpk(st[14], st[15]);
      pl32swap(a0, b0); pl32swap(a1, b1); pl32swap(c0, d0); pl32swap(c1, d1);
      pa[0] = __builtin_bit_cast(bfv8, make_uint4(a0, a1, b0, b1));
      pa[1] = __builtin_bit_cast(bfv8, make_uint4(c0, c1, d0, d1));
    }

    // ---- O += P . V ----
    __builtin_amdgcn_s_setprio(1);
#pragma unroll
    for (int dt = 0; dt < 4; ++dt)
#pragma unroll
      for (int ksub = 0; ksub < 2; ++ksub) {
        bfv8 vf = *(const bfv8*)&lVf[CUR * 4096 + vidx[dt][ksub]];
        oacc[dt] = MFMA32(pa[ksub], vf, oacc[dt]);
      }
    __builtin_amdgcn_s_setprio(0);
  };

  for (int it = 0; it < 42; ++it) {
    tile(ic<0>{}, ic<4>{}, ic<1>{});
    tile(ic<1>{}, ic<4>{}, ic<1>{});
    tile(ic<2>{}, ic<4>{}, ic<1>{});
  }
  tile(ic<0>{}, ic<4>{}, ic<0>{});
  tile(ic<1>{}, ic<0>{}, ic<0>{});

  float linv = 1.0f / l_run;
#pragma unroll
  for (int r = 0; r < 16; ++r) {
    int qr = (r & 3) + 8 * (r >> 2) + 4 * hi;
    float lr = __shfl(linv, qr);
    float* orow = outp + (size_t)(qb0 + w * 32 + qr) * DIM + h * HD;
#pragma unroll
    for (int dt = 0; dt < 4; ++dt) orow[dt * 32 + l31] = oacc[dt][r] * lr;
  }
#undef STAGE
}

extern "C" void kernel_launch(void* const* d_in, const int* in_sizes, int n_in,
                              void* d_out, int out_size, void* d_ws, size_t ws_size,
                              hipStream_t stream) {
  const float* hs = (const float*)d_in[0];
  const float* cosT = (const float*)d_in[1];
  const float* sinT = (const float*)d_in[2];
  const float* Wq = (const float*)d_in[3];
  const float* bq = (const float*)d_in[4];
  const float* Wk = (const float*)d_in[5];
  const float* bk = (const float*)d_in[6];
  const float* Wv = (const float*)d_in[7];
  const float* bv = (const float*)d_in[8];
  const float* gq = (const float*)d_in[9];
  const float* gk = (const float*)d_in[10];
  float* out = (float*)d_out;

  char* ws = (char*)d_ws;
  const size_t SZ_HS = (size_t)SEQ * DIM * 2;
  const size_t SZ_W = (size_t)DIM * DIM * 2;
  const size_t SZ_HEAD = (size_t)NH * SEQ * HD * 2;
  unsigned short* hsb = (unsigned short*)ws;               ws += SZ_HS;
  unsigned short* WqT = (unsigned short*)ws;               ws += SZ_W;
  unsigned short* WkT = (unsigned short*)ws;               ws += SZ_W;
  unsigned short* WvT = (unsigned short*)ws;               ws += SZ_W;
  unsigned short* q_b = (unsigned short*)ws;               ws += SZ_HEAD;
  unsigned short* k_b = (unsigned short*)ws;               ws += SZ_HEAD;
  unsigned short* v_b = (unsigned short*)ws;               ws += SZ_HEAD;
  unsigned short* vtr = (unsigned short*)ws;               ws += SZ_HEAD;

  int n4 = SEQ * DIM / 4;
  k_cast<<<dim3(n4 / 256), dim3(256), 0, stream>>>((const float4*)hs, (us4*)hsb, n4);
  k_transW<<<dim3(48, 48, 3), dim3(256), 0, stream>>>(Wq, Wk, Wv, WqT, WkT, WvT);
  k_gemm<<<dim3(24, 32, 3), dim3(256), 0, stream>>>(hsb, WqT, WkT, WvT, bq, bk, bv,
                                                    q_b, k_b, v_b);
  k_rmsrope<<<dim3(2 * NH * SEQ / 4), dim3(256), 0, stream>>>(q_b, k_b, cosT, sinT, gq, gk);
  k_transV<<<dim3(64, 24), dim3(256), 0, stream>>>(v_b, vtr);
  k_attn<<<dim3(32, 24), dim3(256), 0, stream>>>(q_b, k_b, vtr, out);
}

// Round 12
// 541.216 us; speedup vs baseline: 1.4428x; 1.0545x over previous
//
#include <hip/hip_runtime.h>
#include <hip/hip_bf16.h>
#include <stdint.h>

#define DIM 3072
#define SEQ 4096
#define NH 24
#define HD 128

typedef __hip_bfloat16 bf16;
typedef __bf16 bfv8 __attribute__((ext_vector_type(8)));
typedef float f32x4 __attribute__((ext_vector_type(4)));
typedef float f32x16 __attribute__((ext_vector_type(16)));
typedef unsigned short us4 __attribute__((ext_vector_type(4)));
typedef unsigned short us8 __attribute__((ext_vector_type(8)));

template <int N> struct ic { static constexpr int value = N; };

__device__ __forceinline__ void async16(void* lds, const void* g) {
  __builtin_amdgcn_global_load_lds((const __attribute__((address_space(1))) void*)g,
                                   (__attribute__((address_space(3))) void*)lds, 16, 0, 0);
}

__device__ __forceinline__ unsigned short f2bf(float f) {
  unsigned int u = __builtin_bit_cast(unsigned int, f);
  u += 0x7fffu + ((u >> 16) & 1u);
  return (unsigned short)(u >> 16);
}
__device__ __forceinline__ float bf2f(unsigned short b) {
  return __builtin_bit_cast(float, (unsigned int)b << 16);
}
__device__ __forceinline__ unsigned int cvtpk(float lo, float hi) {
  unsigned int r;
  asm("v_cvt_pk_bf16_f32 %0, %1, %2" : "=v"(r) : "v"(lo), "v"(hi));
  return r;
}
__device__ __forceinline__ void pl32swap(unsigned int& a, unsigned int& b) {
  asm volatile("v_permlane32_swap_b32 %0, %1" : "+v"(a), "+v"(b));
}
#if __has_builtin(__builtin_amdgcn_exp2f)
__device__ __forceinline__ float fexp2(float x) { return __builtin_amdgcn_exp2f(x); }
#else
__device__ __forceinline__ float fexp2(float x) { return exp2f(x); }
#endif

#define MFMA16(a, b, c) __builtin_amdgcn_mfma_f32_16x16x32_bf16((a), (b), (c), 0, 0, 0)
#define MFMA32(a, b, c) __builtin_amdgcn_mfma_f32_32x32x16_bf16((a), (b), (c), 0, 0, 0)

// ---------------- kernel 1: fp32 -> bf16 cast (hidden states) ----------------
__global__ __launch_bounds__(256) void k_cast(const float4* __restrict__ in,
                                              us4* __restrict__ o, int n4) {
  int i = blockIdx.x * 256 + threadIdx.x;
  if (i >= n4) return;
  float4 v = in[i];
  us4 r;
  r.x = f2bf(v.x); r.y = f2bf(v.y); r.z = f2bf(v.z); r.w = f2bf(v.w);
  o[i] = r;
}

// ------------- kernel 2: transpose-cast W (KxN fp32) -> WT (NxK bf16) -------------
__global__ __launch_bounds__(256) void k_transW(const float* __restrict__ W0,
    const float* __restrict__ W1, const float* __restrict__ W2,
    unsigned short* __restrict__ T0, unsigned short* __restrict__ T1,
    unsigned short* __restrict__ T2) {
  int z = blockIdx.z;
  const float* W = (z == 0) ? W0 : (z == 1) ? W1 : W2;
  unsigned short* T = (z == 0) ? T0 : (z == 1) ? T1 : T2;
  int kb = blockIdx.y * 64;
  int nb = blockIdx.x * 64;
  __shared__ float tile[64 * 64];
  int t = threadIdx.x;
#pragma unroll
  for (int p = 0; p < 4; ++p) {
    int cid = p * 256 + t;
    int row = cid >> 4, c4 = cid & 15;
    int slot = (c4 + (row >> 3)) & 15;
    float4 v = *(const float4*)&W[(size_t)(kb + row) * DIM + nb + c4 * 4];
    *(float4*)&tile[row * 64 + slot * 4] = v;
  }
  __syncthreads();
#pragma unroll
  for (int p = 0; p < 2; ++p) {
    int cid = p * 256 + t;
    int nl = cid >> 3, c8 = cid & 7;
    us8 o;
#pragma unroll
    for (int j = 0; j < 8; ++j) {
      int k = c8 * 8 + j;
      int slot = ((nl >> 2) + (k >> 3)) & 15;
      o[j] = f2bf(tile[k * 64 + slot * 4 + (nl & 3)]);
    }
    *(us8*)&T[(size_t)(nb + nl) * DIM + kb + c8 * 8] = o;
  }
}

// ------------- kernel 3: GEMM  out[s][n] = hs[s][:] . WT[n][:] + bias[n] -------------
__global__ __launch_bounds__(256, 3) void k_gemm(const unsigned short* __restrict__ A,
    const unsigned short* __restrict__ B0, const unsigned short* __restrict__ B1,
    const unsigned short* __restrict__ B2, const float* __restrict__ c0,
    const float* __restrict__ c1, const float* __restrict__ c2,
    unsigned short* __restrict__ o0, unsigned short* __restrict__ o1,
    unsigned short* __restrict__ o2) {
  const int z = blockIdx.z;
  const unsigned short* Bt = (z == 0) ? B0 : (z == 1) ? B1 : B2;
  const float* bias = (z == 0) ? c0 : (z == 1) ? c1 : c2;
  unsigned short* outp = (z == 0) ? o0 : (z == 1) ? o1 : o2;
  const int nb = blockIdx.x * 128;
  const int mb = blockIdx.y * 128;
  const int t = threadIdx.x;
  const int w = t >> 6, l = t & 63;
  const int wr = w >> 1, wc = w & 1;
  const int lq = l & 15, lg = l >> 4;
  __shared__ unsigned short lA[128 * 64];
  __shared__ unsigned short lB[128 * 64];
  f32x4 acc[4][4];
#pragma unroll
  for (int i = 0; i < 4; ++i)
#pragma unroll
    for (int j = 0; j < 4; ++j) acc[i][j] = (f32x4){0.f, 0.f, 0.f, 0.f};

  for (int kb = 0; kb < DIM; kb += 64) {
    __syncthreads();
#pragma unroll
    for (int r = 0; r < 4; ++r) {
      int row = (w * 4 + r) * 8 + (l >> 3);
      int sl = (l & 7) ^ (row & 7);
      async16(&lA[(w * 4 + r) * 512], A + (size_t)(mb + row) * DIM + kb + sl * 8);
      async16(&lB[(w * 4 + r) * 512], Bt + (size_t)(nb + row) * DIM + kb + sl * 8);
    }
    __syncthreads();
#pragma unroll
    for (int kc = 0; kc < 2; ++kc) {
      bfv8 af[4], bfv[4];
#pragma unroll
      for (int mf = 0; mf < 4; ++mf) {
        int row = wr * 64 + mf * 16 + lq;
        af[mf] = *(const bfv8*)&lA[row * 64 + (((kc * 4 + lg) ^ (row & 7)) * 8)];
      }
#pragma unroll
      for (int nf = 0; nf < 4; ++nf) {
        int row = wc * 64 + nf * 16 + lq;
        bfv[nf] = *(const bfv8*)&lB[row * 64 + (((kc * 4 + lg) ^ (row & 7)) * 8)];
      }
#pragma unroll
      for (int mf = 0; mf < 4; ++mf)
#pragma unroll
        for (int nf = 0; nf < 4; ++nf)
          acc[mf][nf] = MFMA16(af[mf], bfv[nf], acc[mf][nf]);
    }
  }
#pragma unroll
  for (int nf = 0; nf < 4; ++nf) {
    int n = nb + wc * 64 + nf * 16 + lq;
    float bv_ = bias[n];
    int hh = n >> 7, dd = n & 127;
    unsigned short* obase = outp + (size_t)hh * SEQ * HD + dd;
#pragma unroll
    for (int mf = 0; mf < 4; ++mf) {
      int srow = mb + wr * 64 + mf * 16 + lg * 4;
#pragma unroll
      for (int r = 0; r < 4; ++r)
        obase[(size_t)(srow + r) * HD] = f2bf(acc[mf][nf][r] + bv_);
    }
  }
}

// ------------- kernel 4: per-(h,s)-row RMSNorm + RoPE (in place, bf16) -------------
__global__ __launch_bounds__(256) void k_rmsrope(unsigned short* __restrict__ qb,
    unsigned short* __restrict__ kbuf, const float* __restrict__ cosT,
    const float* __restrict__ sinT, const float* __restrict__ gq,
    const float* __restrict__ gk) {
  int rowid = blockIdx.x * 4 + (threadIdx.x >> 6);
  int l = threadIdx.x & 63;
  int which = (rowid >= NH * SEQ) ? 1 : 0;
  int r2 = which ? rowid - NH * SEQ : rowid;
  int hh = r2 >> 12;
  int s = r2 & 4095;
  unsigned short* base = (which ? kbuf : qb) + ((size_t)hh * SEQ + s) * HD + 2 * l;
  const float* g = which ? gk : gq;
  unsigned int u = *(const unsigned int*)base;
  float x0 = bf2f((unsigned short)(u & 0xffffu));
  float x1 = bf2f((unsigned short)(u >> 16));
  float ss = x0 * x0 + x1 * x1;
#pragma unroll
  for (int o = 1; o < 64; o <<= 1) ss += __shfl_xor(ss, o);
  float rr = rsqrtf(ss * (1.0f / 128.0f) + 1e-6f);
  int d0 = 2 * l;
  float c0v = cosT[s * HD + d0], c1v = cosT[s * HD + d0 + 1];
  float s0v = sinT[s * HD + d0], s1v = sinT[s * HD + d0 + 1];
  float y0 = x0 * rr * g[d0];
  float y1 = x1 * rr * g[d0 + 1];
  float o0 = y0 * c0v - y1 * s0v;
  float o1 = y1 * c1v + y0 * s1v;
  if (!which) { o0 *= 0.1275174373f; o1 *= 0.1275174373f; } // log2(e)/sqrt(128)
  *(unsigned int*)base = (unsigned int)f2bf(o0) | ((unsigned int)f2bf(o1) << 16);
}

// ------------- kernel 5: V transpose  v[h][s][d] -> vt[h][d][s] -------------
__global__ __launch_bounds__(256) void k_transV(const unsigned short* __restrict__ vb,
                                                unsigned short* __restrict__ vt) {
  int hh = blockIdx.y;
  int sb = blockIdx.x * 64;
  __shared__ unsigned short tile[64 * 128];
  int t = threadIdx.x;
#pragma unroll
  for (int p = 0; p < 4; ++p) {
    int cid = p * 256 + t;
    int row = cid >> 4, c = cid & 15;
    int slot = (c + (row >> 3)) & 15;
    us8 v = *(const us8*)&vb[((size_t)hh * SEQ + sb + row) * HD + c * 8];
    *(us8*)&tile[row * 128 + slot * 8] = v;
  }
  __syncthreads();
#pragma unroll
  for (int p = 0; p < 4; ++p) {
    int cid = p * 256 + t;
    int d = cid >> 3, c8 = cid & 7;
    us8 o;
#pragma unroll
    for (int j = 0; j < 8; ++j) {
      int s = c8 * 8 + j;
      int slot = ((d >> 3) + (s >> 3)) & 15;
      o[j] = tile[s * 128 + slot * 8 + (d & 7)];
    }
    *(us8*)&vt[((size_t)hh * HD + d) * SEQ + sb + c8 * 8] = o;
  }
}

// ------------- kernel 6: flash attention, R12: 2 KV-tiles per barrier phase -------------
// 4 waves x 32q. Per phase: two independent QK chains (2x ILP), half the barriers,
// 2 pair-buffers (64KB -> 2 blocks/CU, 2 waves/SIMD from different blocks).
// l_run cross-half shuffle deferred to epilogue (partial sums per lane are exact).
__global__ __launch_bounds__(256, 2) void k_attn(const unsigned short* __restrict__ qg,
    const unsigned short* __restrict__ kg, const unsigned short* __restrict__ vtg,
    float* __restrict__ outp) {
  const int h = blockIdx.y;
  const int qb0 = blockIdx.x * 128;
  const int t = threadIdx.x;
  const int w = t >> 6, l = t & 63;
  const int l31 = l & 31, hi = l >> 5;

  __shared__ unsigned short lKf[2 * 8192];  // [2][ KA 32x128 | KB 32x128 ]
  __shared__ unsigned short lVf[2 * 8192];  // [2][ VA 128x32 | VB 128x32 ]

  bfv8 qf[8];
  {
    const unsigned short* qrow = qg + ((size_t)h * SEQ + qb0 + w * 32 + l31) * HD + hi * 8;
#pragma unroll
    for (int ks = 0; ks < 8; ++ks) qf[ks] = *(const bfv8*)(qrow + ks * 16);
  }

  int kidx[8], vidx[4][2];
#pragma unroll
  for (int ks = 0; ks < 8; ++ks)
    kidx[ks] = l31 * 128 + (((ks * 2 + hi) ^ (l31 & 7) ^ ((l31 >> 3) & 1)) * 8);
#pragma unroll
  for (int dt = 0; dt < 4; ++dt)
#pragma unroll
    for (int ksub = 0; ksub < 2; ++ksub)
      vidx[dt][ksub] =
          (dt * 32 + l31) * 32 + (((ksub * 2 + hi) ^ (l31 & 3) ^ ((l31 >> 2) & 3)) * 8);

  const unsigned short *kp0, *kp1, *vp0, *vp1;
  {
    int kr0 = w * 4 + (l >> 4), kr1 = 16 + kr0;
    kp0 = kg + ((size_t)h * SEQ + kr0) * HD + (((l & 15) ^ (kr0 & 7) ^ ((kr0 >> 3) & 1)) * 8);
    kp1 = kg + ((size_t)h * SEQ + kr1) * HD + (((l & 15) ^ (kr1 & 7) ^ ((kr1 >> 3) & 1)) * 8);
    int vr0 = w * 16 + (l >> 2), vr1 = 64 + vr0;
    vp0 = vtg + ((size_t)h * HD + vr0) * SEQ + (((l & 3) ^ (vr0 & 3) ^ ((vr0 >> 2) & 3)) * 8);
    vp1 = vtg + ((size_t)h * HD + vr1) * SEQ + (((l & 3) ^ (vr1 & 3) ^ ((vr1 >> 2) & 3)) * 8);
  }

  // stage one PAIR (2 KV tiles = 64 kv) into buffer B; bump ptrs by 64
#define STAGE(B)                                                              \
  do {                                                                        \
    async16(&lKf[(B) * 8192 + w * 512], kp0);                                 \
    async16(&lKf[(B) * 8192 + 2048 + w * 512], kp1);                          \
    async16(&lKf[(B) * 8192 + 4096 + w * 512], kp0 + 32 * HD);                \
    async16(&lKf[(B) * 8192 + 6144 + w * 512], kp1 + 32 * HD);                \
    async16(&lVf[(B) * 8192 + w * 512], vp0);                                 \
    async16(&lVf[(B) * 8192 + 2048 + w * 512], vp1);                          \
    async16(&lVf[(B) * 8192 + 4096 + w * 512], vp0 + 32);                     \
    async16(&lVf[(B) * 8192 + 6144 + w * 512], vp1 + 32);                     \
    kp0 += 64 * HD; kp1 += 64 * HD; vp0 += 64; vp1 += 64;                     \
  } while (0)

  f32x16 oacc[4];
#pragma unroll
  for (int dt = 0; dt < 4; ++dt)
#pragma unroll
    for (int r = 0; r < 16; ++r) oacc[dt][r] = 0.f;
  float l_run = 0.f;  // per-lane partial (own kv-half); completed in epilogue

  STAGE(0);

  auto phase = [&](auto bufc, auto stagec) {
    constexpr int CUR = decltype(bufc)::value;
    constexpr int DOSTAGE = decltype(stagec)::value;
    // own pair loads (issued one full phase ago) done, then block-wide barrier
    asm volatile("s_waitcnt vmcnt(0)" ::: "memory");
    __builtin_amdgcn_s_barrier();
    __builtin_amdgcn_sched_barrier(0);
    if constexpr (DOSTAGE) STAGE(CUR ^ 1);
    __builtin_amdgcn_sched_barrier(0);

    // ---- two independent QK chains ----
    f32x16 sa, sb;
#pragma unroll
    for (int r = 0; r < 16; ++r) { sa[r] = 0.f; sb[r] = 0.f; }
    __builtin_amdgcn_s_setprio(1);
#pragma unroll
    for (int ks = 0; ks < 8; ++ks) {
      bfv8 kfa = *(const bfv8*)&lKf[CUR * 8192 + kidx[ks]];
      bfv8 kfb = *(const bfv8*)&lKf[CUR * 8192 + 4096 + kidx[ks]];
      sa = MFMA32(kfa, qf[ks], sa);
      sb = MFMA32(kfb, qf[ks], sb);
    }
    __builtin_amdgcn_s_setprio(0);

    // ---- max-free softmax (exp2 domain), partial row-sums only ----
#pragma unroll
    for (int r = 0; r < 16; ++r) { sa[r] = fexp2(sa[r]); sb[r] = fexp2(sb[r]); }
    {
      float a0 = (sa[0] + sa[1]) + (sa[2] + sa[3]);
      float a1 = (sa[4] + sa[5]) + (sa[6] + sa[7]);
      float a2 = (sa[8] + sa[9]) + (sa[10] + sa[11]);
      float a3 = (sa[12] + sa[13]) + (sa[14] + sa[15]);
      float b0 = (sb[0] + sb[1]) + (sb[2] + sb[3]);
      float b1 = (sb[4] + sb[5]) + (sb[6] + sb[7]);
      float b2 = (sb[8] + sb[9]) + (sb[10] + sb[11]);
      float b3 = (sb[12] + sb[13]) + (sb[14] + sb[15]);
      l_run += ((a0 + a1) + (a2 + a3)) + ((b0 + b1) + (b2 + b3));
    }

    // ---- pack both P tiles into PV A-frags ----
    bfv8 paA[2], paB[2];
    {
      unsigned int a0 = cvtpk(sa[0], sa[1]), a1 = cvtpk(sa[2], sa[3]);
      unsigned int b0 = cvtpk(sa[4], sa[5]), b1 = cvtpk(sa[6], sa[7]);
      unsigned int c0 = cvtpk(sa[8], sa[9]), c1 = cvtpk(sa[10], sa[11]);
      unsigned int d0 = cvtpk(sa[12], sa[13]), d1 = cvtpk(sa[14], sa[15]);
      pl32swap(a0, b0); pl32swap(a1, b1); pl32swap(c0, d0); pl32swap(c1, d1);
      paA[0] = __builtin_bit_cast(bfv8, make_uint4(a0, a1, b0, b1));
      paA[1] = __builtin_bit_cast(bfv8, make_uint4(c0, c1, d0, d1));
      a0 = cvtpk(sb[0], sb[1]); a1 = cvtpk(sb[2], sb[3]);
      b0 = cvtpk(sb[4], sb[5]); b1 = cvtpk(sb[6], sb[7]);
      c0 = cvtpk(sb[8], sb[9]); c1 = cvtpk(sb[10], sb[11]);
      d0 = cvtpk(sb[12], sb[13]); d1 = cvtpk(sb[14], sb[15]);
      pl32swap(a0, b0); pl32swap(a1, b1); pl32swap(c0, d0); pl32swap(c1, d1);
      paB[0] = __builtin_bit_cast(bfv8, make_uint4(a0, a1, b0, b1));
      paB[1] = __builtin_bit_cast(bfv8, make_uint4(c0, c1, d0, d1));
    }

    // ---- O += P.V for both tiles (4 independent dt chains, depth 4) ----
    __builtin_amdgcn_s_setprio(1);
#pragma unroll
    for (int dt = 0; dt < 4; ++dt) {
#pragma unroll
      for (int ksub = 0; ksub < 2; ++ksub) {
        bfv8 vfa = *(const bfv8*)&lVf[CUR * 8192 + vidx[dt][ksub]];
        oacc[dt] = MFMA32(paA[ksub], vfa, oacc[dt]);
      }
#pragma unroll
      for (int ksub = 0; ksub < 2; ++ksub) {
        bfv8 vfb = *(const bfv8*)&lVf[CUR * 8192 + 4096 + vidx[dt][ksub]];
        oacc[dt] = MFMA32(paB[ksub], vfb, oacc[dt]);
      }
    }
    __builtin_amdgcn_s_setprio(0);
  };

  // 64 phases (2 tiles each). Phase p uses buf p&1, stages (p+1)&1.
  for (int it = 0; it < 31; ++it) {
    phase(ic<0>{}, ic<1>{});
    phase(ic<1>{}, ic<1>{});
  }
  phase(ic<0>{}, ic<1>{});
  phase(ic<1>{}, ic<0>{});

  // ---- epilogue: complete l_run across lane-halves, divide, store ----
  l_run += __shfl_xor(l_run, 32);
  float linv = 1.0f / l_run;
#pragma unroll
  for (int r = 0; r < 16; ++r) {
    int qr = (r & 3) + 8 * (r >> 2) + 4 * hi;
    float lr = __shfl(linv, qr);
    float* orow = outp + (size_t)(qb0 + w * 32 + qr) * DIM + h * HD;
#pragma unroll
    for (int dt = 0; dt < 4; ++dt) orow[dt * 32 + l31] = oacc[dt][r] * lr;
  }
#undef STAGE
}

extern "C" void kernel_launch(void* const* d_in, const int* in_sizes, int n_in,
                              void* d_out, int out_size, void* d_ws, size_t ws_size,
                              hipStream_t stream) {
  const float* hs = (const float*)d_in[0];
  const float* cosT = (const float*)d_in[1];
  const float* sinT = (const float*)d_in[2];
  const float* Wq = (const float*)d_in[3];
  const float* bq = (const float*)d_in[4];
  const float* Wk = (const float*)d_in[5];
  const float* bk = (const float*)d_in[6];
  const float* Wv = (const float*)d_in[7];
  const float* bv = (const float*)d_in[8];
  const float* gq = (const float*)d_in[9];
  const float* gk = (const float*)d_in[10];
  float* out = (float*)d_out;

  char* ws = (char*)d_ws;
  const size_t SZ_HS = (size_t)SEQ * DIM * 2;
  const size_t SZ_W = (size_t)DIM * DIM * 2;
  const size_t SZ_HEAD = (size_t)NH * SEQ * HD * 2;
  unsigned short* hsb = (unsigned short*)ws;               ws += SZ_HS;
  unsigned short* WqT = (unsigned short*)ws;               ws += SZ_W;
  unsigned short* WkT = (unsigned short*)ws;               ws += SZ_W;
  unsigned short* WvT = (unsigned short*)ws;               ws += SZ_W;
  unsigned short* q_b = (unsigned short*)ws;               ws += SZ_HEAD;
  unsigned short* k_b = (unsigned short*)ws;               ws += SZ_HEAD;
  unsigned short* v_b = (unsigned short*)ws;               ws += SZ_HEAD;
  unsigned short* vtr = (unsigned short*)ws;               ws += SZ_HEAD;

  int n4 = SEQ * DIM / 4;
  k_cast<<<dim3(n4 / 256), dim3(256), 0, stream>>>((const float4*)hs, (us4*)hsb, n4);
  k_transW<<<dim3(48, 48, 3), dim3(256), 0, stream>>>(Wq, Wk, Wv, WqT, WkT, WvT);
  k_gemm<<<dim3(24, 32, 3), dim3(256), 0, stream>>>(hsb, WqT, WkT, WvT, bq, bk, bv,
                                                    q_b, k_b, v_b);
  k_rmsrope<<<dim3(2 * NH * SEQ / 4), dim3(256), 0, stream>>>(q_b, k_b, cosT, sinT, gq, gk);
  k_transV<<<dim3(64, 24), dim3(256), 0, stream>>>(v_b, vtr);
  k_attn<<<dim3(32, 24), dim3(256), 0, stream>>>(q_b, k_b, vtr, out);
}